// Round 4
// baseline (552.158 us; speedup 1.0000x reference)
//
#include <hip/hip_runtime.h>
#include <hip/hip_bf16.h>
#include <stdint.h>

#define B_DIM 8192
#define IN_DIM 4096
#define OUT_DIM 4096
#define NT (IN_DIM / 64)   // 64 K-tiles of BK=64

typedef __attribute__((ext_vector_type(8))) short s16x8;
typedef __attribute__((ext_vector_type(4))) float f32x4;
typedef __attribute__((ext_vector_type(16))) float f32x16;

__device__ __forceinline__ unsigned short f2bf_rn(float f) {
    unsigned int u = __float_as_uint(f);
    u = (u + 0x7FFFu + ((u >> 16) & 1u)) >> 16;
    return (unsigned short)u;
}

__device__ __forceinline__ void async16(unsigned short* l, const unsigned short* g) {
    __builtin_amdgcn_global_load_lds(
        (const __attribute__((address_space(1))) void*)g,
        (__attribute__((address_space(3))) void*)l, 16, 0, 0);
}

// ---- Kernel 1: fused weight-quant (blocks 0..4095) + x->bf16 (rest) --------
__global__ __launch_bounds__(256) void prep(
    const float* __restrict__ W, const float* __restrict__ b,
    const float* __restrict__ act_sf, const float* __restrict__ x,
    unsigned short* __restrict__ wq, unsigned short* __restrict__ xq,
    float* __restrict__ fc_sf_out, float* __restrict__ bb,
    float* __restrict__ gmax)
{
    __shared__ float red[4];
    int t = threadIdx.x;
    if (blockIdx.x < OUT_DIM) {
        int o = blockIdx.x;
        const float4* Wr = (const float4*)(W + (size_t)o * IN_DIM);
        float4 v[4];
        float amax = 0.f;
#pragma unroll
        for (int j = 0; j < 4; ++j) {
            v[j] = Wr[t + j * 256];
            amax = fmaxf(amax, fmaxf(fmaxf(fabsf(v[j].x), fabsf(v[j].y)),
                                     fmaxf(fabsf(v[j].z), fabsf(v[j].w))));
        }
#pragma unroll
        for (int off = 32; off > 0; off >>= 1)
            amax = fmaxf(amax, __shfl_down(amax, off, 64));
        if ((t & 63) == 0) red[t >> 6] = amax;
        __syncthreads();
        float wmax = fmaxf(fmaxf(red[0], red[1]), fmaxf(red[2], red[3]));
        float sf = fmaxf(wmax, 1e-8f) / 127.0f;   // fc_sf

        unsigned short* wr = wq + (size_t)o * IN_DIM;
#pragma unroll
        for (int j = 0; j < 4; ++j) {
            ushort4 q;
            q.x = f2bf_rn(fminf(fmaxf(rintf(v[j].x / sf), -128.f), 127.f));
            q.y = f2bf_rn(fminf(fmaxf(rintf(v[j].y / sf), -128.f), 127.f));
            q.z = f2bf_rn(fminf(fmaxf(rintf(v[j].z / sf), -128.f), 127.f));
            q.w = f2bf_rn(fminf(fmaxf(rintf(v[j].w / sf), -128.f), 127.f));
            ((ushort4*)wr)[t + j * 256] = q;
        }
        if (t == 0) {
            fc_sf_out[o] = sf;
            float bsf = sf * act_sf[0];          // bias_sf
            float bi = rintf(b[o] / bsf);        // b_int
            bb[o] = bi * bsf;                    // folded bias
            if (o == 0) gmax[0] = 0.f;           // ws is poisoned each launch
        }
    } else {
        size_t i = ((size_t)(blockIdx.x - OUT_DIM) * 256 + t) * 8;
#pragma unroll
        for (int j = 0; j < 2; ++j) {
            float4 v = *(const float4*)(x + i + j * 4);
            ushort4 q;
            q.x = f2bf_rn(v.x); q.y = f2bf_rn(v.y);
            q.z = f2bf_rn(v.z); q.w = f2bf_rn(v.w);
            *(ushort4*)(xq + i + j * 4) = q;
        }
    }
}

// ---- Kernel 2: 256x256-tile skewed-pipeline GEMM, 32x32x16 MFMA ------------
// R4 vs R3: switch 16x16x32 -> 32x32x16 bf16 MFMA (higher ceiling 2382 vs
// 2075 TF; half the MFMA instruction count). Schedule/staging/swizzle/waits
// are IDENTICAL to R3's verified pipeline (same per-phase read volumes).
// Fragment mapping (32x32x16): A: lane holds row=lane&31 of its M-block,
//   k = 16*ks + 8*(lane>>5) + j (8 contiguous bf16 = 1 ds_read_b128).
// C/D: col=lane&31, row=(reg&3)+8*(reg>>2)+4*(lane>>5)  [m74/m101-verified].
// Wave (wm,wn) owns M-blocks {4X+2mh+wm} (32 rows) and N-blocks {4y+wn}.
// acc[m][y] with m=2X+mh -> epilogue phase ph consumes exactly acc[ph][y]
// (global M-block 2*ph+wm), so the 64x260 transpose stage is unchanged.
template <bool CB16>
__global__ __launch_bounds__(512) void gemm_bt(
    const unsigned short* __restrict__ A, const unsigned short* __restrict__ Bw,
    const float* __restrict__ fc_sf, const float* __restrict__ bb,
    void* __restrict__ Cout, float* __restrict__ gmax)
{
    __shared__ __align__(16) unsigned char smem[131072];
    unsigned short* lds = (unsigned short*)smem;   // A: buf0/buf1 32K each | B: 32K each
    float* stage = (float*)smem;                   // epilogue 64x260 fp32
    float* redm  = (float*)(smem + 131040);        // 8 floats (used only after full drain)

    int t = threadIdx.x;
    // XCD-aware swizzle: 512 wgs, 512 % 8 == 0 -> bijective remap.
    int bid = ((blockIdx.x & 7) << 6) | (blockIdx.x >> 3);
    int bm = bid >> 4, bn = bid & 15;              // 32 x 16 tiles
    int m0 = bm << 8, n0 = bn << 8;

    int w = t >> 6, lane = t & 63;
    int wm = w & 1, wn = w >> 1;                   // 2M x 4N wave grid
    int l31 = lane & 31, lhi = lane >> 5, l7 = lane & 7;

    // per-k-step chunk-slot offsets (u16 units): chunk = (2*ks + lhi) ^ (row&7)
    int co32[4];
#pragma unroll
    for (int ks = 0; ks < 4; ++ks)
        co32[ks] = (((2 * ks + lhi) ^ l7) << 3);
    int aOff = ((wm << 5) + l31) << 6;             // (wm*32 + l31) * 64
    int bOff = 32768 + (((wn << 5) + l31) << 6);   // B base (64KB) + row offset

    // Staging: half-tile = 128 rows x 64 cols bf16 = 16 KB; thread t owns
    // slot t (rows 0..63) and t+512 (rows 64..127). Source pre-swizzled.
    int r0 = t >> 3;
    int cs = ((t & 7) ^ (r0 & 7)) << 3;
    const unsigned short* gA = A + (size_t)(m0 + r0) * IN_DIM + cs;
    const unsigned short* gB = Bw + (size_t)(n0 + r0) * IN_DIM + cs;
    unsigned short* ldsA = lds + t * 8;
    unsigned short* ldsB = lds + 32768 + t * 8;

#define STA(u, hf) { int uu_ = (u) < NT ? (u) : ((u) - 2 < NT ? (u) - 2 : (u) - 4); \
    const unsigned short* s_ = gA + (size_t)((hf) * 128) * IN_DIM + uu_ * 64;       \
    unsigned short* d_ = ldsA + ((uu_ & 1) << 14) + ((hf) << 13);                   \
    async16(d_, s_); async16(d_ + 4096, s_ + (size_t)64 * IN_DIM); }
#define STB(u, hf) { int uu_ = (u) < NT ? (u) : ((u) - 2 < NT ? (u) - 2 : (u) - 4); \
    const unsigned short* s_ = gB + (size_t)((hf) * 128) * IN_DIM + uu_ * 64;       \
    unsigned short* d_ = ldsB + ((uu_ & 1) << 14) + ((hf) << 13);                   \
    async16(d_, s_); async16(d_ + 4096, s_ + (size_t)64 * IN_DIM); }

// A group: 2 M-sub-blocks (64 rows apart = +4096 u16) x 4 k-steps = 8 ds_read_b128
#define RD_A(dst, base) _Pragma("unroll") \
    for (int mh_ = 0; mh_ < 2; ++mh_) { _Pragma("unroll") \
        for (int ks_ = 0; ks_ < 4; ++ks_) \
            dst[mh_][ks_] = *(const s16x8*)((base) + mh_ * 4096 + co32[ks_]); }
// B group: 1 N-block x 4 k-steps = 4 ds_read_b128
#define RD_B(dst, base) _Pragma("unroll") \
    for (int ks_ = 0; ks_ < 4; ++ks_) \
        dst[ks_] = *(const s16x8*)((base) + co32[ks_]);

#define QUAD(X, Y, AF, BF) _Pragma("unroll") \
    for (int mh_ = 0; mh_ < 2; ++mh_) { _Pragma("unroll") \
        for (int ks_ = 0; ks_ < 4; ++ks_) \
            acc[2 * (X) + mh_][Y] = __builtin_amdgcn_mfma_f32_32x32x16_bf16( \
                AF[mh_][ks_], BF[ks_], acc[2 * (X) + mh_][Y], 0, 0, 0); }

#define PHASE(RD, NCNT, ST, MM) \
    RD; \
    asm volatile("s_waitcnt lgkmcnt(" #NCNT ")" ::: "memory"); \
    __builtin_amdgcn_sched_barrier(0); \
    asm volatile("s_waitcnt vmcnt(10)" ::: "memory"); \
    __builtin_amdgcn_s_barrier(); \
    ST; \
    __builtin_amdgcn_s_setprio(1); \
    MM; \
    __builtin_amdgcn_s_setprio(0);

    f32x16 acc[4][2];
#pragma unroll
    for (int m = 0; m < 4; ++m)
#pragma unroll
        for (int y = 0; y < 2; ++y)
#pragma unroll
            for (int r = 0; r < 16; ++r)
                acc[m][y][r] = 0.f;

    s16x8 a0[2][4], a1[2][4], b0[4], b1[4];

    // ---- prologue: bulk-stage 7 half-tiles in read order -------------------
    // S1=A(0,0) S2=B(0,0) S3=B(0,1) S4=A(0,1) S5=A(1,0) S6=B(1,0) S7=B(1,1)
    STA(0, 0); STB(0, 0); STB(0, 1); STA(0, 1); STA(1, 0); STB(1, 0); STB(1, 1);
    asm volatile("s_waitcnt vmcnt(12)" ::: "memory");   // drain S1 (all waves) ...
    __builtin_amdgcn_s_barrier();                       // ... before anyone reads it
    // p0: read A0(0)=S1; stage S8=A(1,1)
    RD_A(a0, lds + aOff);
    asm volatile("s_waitcnt lgkmcnt(8)" ::: "memory");
    __builtin_amdgcn_sched_barrier(0);
    asm volatile("s_waitcnt vmcnt(10)" ::: "memory");
    __builtin_amdgcn_s_barrier();
    STA(1, 1);
    // p1: read B0(0)=S2; stage S9=A(2,0)
    RD_B(b0, lds + bOff);
    asm volatile("s_waitcnt lgkmcnt(4)" ::: "memory");
    __builtin_amdgcn_sched_barrier(0);
    asm volatile("s_waitcnt vmcnt(10)" ::: "memory");
    __builtin_amdgcn_s_barrier();
    STA(2, 0);

    // ---- main loop: 2 K-tiles per iteration, 8 phases ----------------------
    for (int T = 0; T < NT; T += 2) {
        const unsigned short* laT  = lds + ((T & 1) << 14) + aOff;
        const unsigned short* lbT  = lds + ((T & 1) << 14) + bOff;
        const unsigned short* laT1 = lds + (((T + 1) & 1) << 14) + aOff;
        const unsigned short* lbT1 = lds + (((T + 1) & 1) << 14) + bOff;

        PHASE( RD_B(b1, lbT + 8192),  4, STB(T + 2, 0), QUAD(0, 0, a0, b0) ); // Q00(T)
        PHASE( RD_A(a1, laT + 8192),  8, STB(T + 2, 1), QUAD(0, 1, a0, b1) ); // Q01(T)
        PHASE( RD_A(a0, laT1),        8, STA(T + 2, 1), QUAD(1, 0, a1, b0) ); // Q10(T)
        PHASE( RD_B(b0, lbT1),        4, STA(T + 3, 0), QUAD(1, 1, a1, b1) ); // Q11(T)
        PHASE( RD_B(b1, lbT1 + 8192), 4, STB(T + 3, 0), QUAD(0, 0, a0, b0) ); // Q00(T+1)
        PHASE( RD_A(a1, laT1 + 8192), 8, STB(T + 3, 1), QUAD(0, 1, a0, b1) ); // Q01(T+1)
        PHASE( RD_A(a0, laT),         8, STA(T + 3, 1), QUAD(1, 0, a1, b0) ); // Q10(T+1)
        PHASE( RD_B(b0, lbT),         4, STA(T + 4, 0), QUAD(1, 1, a1, b1) ); // Q11(T+1)
    }

    // drain all pending global_load_lds / ds ops before LDS reuse (redm in B-buf1)
    asm volatile("s_waitcnt vmcnt(0) lgkmcnt(0)" ::: "memory");
    __syncthreads();

    // ---- epilogue: scale+bias+ReLU, track max ------------------------------
    float sc[2], bv[2];
#pragma unroll
    for (int y = 0; y < 2; ++y) {
        int col = n0 + (((y << 2) + wn) << 5) + l31;
        sc[y] = fc_sf[col];
        bv[y] = bb[col];
    }
    float tmax = 0.f;
#pragma unroll
    for (int m = 0; m < 4; ++m)
#pragma unroll
        for (int y = 0; y < 2; ++y)
#pragma unroll
            for (int r = 0; r < 16; ++r) {
                float vv = fmaxf(acc[m][y][r] * sc[y] + bv[y], 0.f);
                acc[m][y][r] = vv;
                tmax = fmaxf(tmax, vv);
            }
#pragma unroll
    for (int off = 32; off > 0; off >>= 1)
        tmax = fmaxf(tmax, __shfl_down(tmax, off, 64));
    if (lane == 0) redm[w] = tmax;

    // ---- 4-phase LDS transpose -> contiguous (bf16) C stores ---------------
    // Phase ph covers global rows m0 + ph*64 .. +63 = M-blocks {2ph, 2ph+1};
    // wave (wm) owns M-block 2ph+wm there, which is exactly acc[ph][*].
#pragma unroll
    for (int ph = 0; ph < 4; ++ph) {
        __syncthreads();
#pragma unroll
        for (int y = 0; y < 2; ++y) {
            int col = (((y << 2) + wn) << 5) + l31;
#pragma unroll
            for (int r = 0; r < 16; ++r) {
                int lrow = (wm << 5) + (r & 3) + ((r >> 2) << 3) + (lhi << 2);
                stage[lrow * 260 + col] = acc[ph][y][r];
            }
        }
        __syncthreads();
        int row = t >> 3, ch = t & 7;
        const float* src = stage + row * 260 + ch * 32;
        size_t gbase = (size_t)(m0 + ph * 64 + row) * OUT_DIM + n0 + ch * 32;
        if (CB16) {
            unsigned short* dst = (unsigned short*)Cout + gbase;
#pragma unroll
            for (int j = 0; j < 4; ++j) {
                float4 v0 = *(const float4*)(src + j * 8);
                float4 v1 = *(const float4*)(src + j * 8 + 4);
                s16x8 q;
                q[0] = (short)f2bf_rn(v0.x); q[1] = (short)f2bf_rn(v0.y);
                q[2] = (short)f2bf_rn(v0.z); q[3] = (short)f2bf_rn(v0.w);
                q[4] = (short)f2bf_rn(v1.x); q[5] = (short)f2bf_rn(v1.y);
                q[6] = (short)f2bf_rn(v1.z); q[7] = (short)f2bf_rn(v1.w);
                *(s16x8*)(dst + j * 8) = q;
            }
        } else {
            float* dst = (float*)Cout + gbase;
#pragma unroll
            for (int j = 0; j < 8; ++j)
                *(float4*)(dst + j * 4) = *(const float4*)(src + j * 4);
        }
    }
    if (t == 0) {
        float bmax = redm[0];
#pragma unroll
        for (int i = 1; i < 8; ++i) bmax = fmaxf(bmax, redm[i]);
        atomicMax((int*)gmax, __float_as_int(bmax));   // values >= 0
    }
#undef STA
#undef STB
#undef RD_A
#undef RD_B
#undef QUAD
#undef PHASE
}

// ---- Kernel 3: per-tensor requant, 16 elems/thread -------------------------
// x_min = 0 exactly (post-ReLU) -> zp = 0.
template <bool CB16>
__global__ __launch_bounds__(256) void requant(const void* __restrict__ Cin,
    float* __restrict__ out, const float* __restrict__ gmax,
    float* __restrict__ sf_out)
{
    float sf = fmaxf(gmax[0], 1e-8f) / 255.0f;
    size_t i = ((size_t)blockIdx.x * 256 + threadIdx.x) * 16;
    if (CB16) {
        const unsigned short* cq = (const unsigned short*)Cin + i;
#pragma unroll
        for (int j = 0; j < 4; ++j) {
            ushort4 q = *(const ushort4*)(cq + j * 4);
            float4 v;
            v.x = __uint_as_float((unsigned)q.x << 16);
            v.y = __uint_as_float((unsigned)q.y << 16);
            v.z = __uint_as_float((unsigned)q.z << 16);
            v.w = __uint_as_float((unsigned)q.w << 16);
            v.x = fminf(rintf(v.x / sf), 255.f) * sf;
            v.y = fminf(rintf(v.y / sf), 255.f) * sf;
            v.z = fminf(rintf(v.z / sf), 255.f) * sf;
            v.w = fminf(rintf(v.w / sf), 255.f) * sf;
            *(float4*)(out + i + j * 4) = v;
        }
    } else {
        float* C = out;   // in place
#pragma unroll
        for (int j = 0; j < 4; ++j) {
            float4 v = *(const float4*)(C + i + j * 4);
            v.x = fminf(rintf(v.x / sf), 255.f) * sf;
            v.y = fminf(rintf(v.y / sf), 255.f) * sf;
            v.z = fminf(rintf(v.z / sf), 255.f) * sf;
            v.w = fminf(rintf(v.w / sf), 255.f) * sf;
            *(float4*)(C + i + j * 4) = v;
        }
    }
    if (i == 0) sf_out[0] = sf;
}

extern "C" void kernel_launch(void* const* d_in, const int* in_sizes, int n_in,
                              void* d_out, int out_size, void* d_ws, size_t ws_size,
                              hipStream_t stream)
{
    const float* x      = (const float*)d_in[0];
    const float* act_sf = (const float*)d_in[1];
    const float* W      = (const float*)d_in[2];
    const float* b      = (const float*)d_in[3];

    float* out        = (float*)d_out;                       // [8192*4096] x_out
    float* fc_sf_out  = out + (size_t)B_DIM * OUT_DIM;       // [4096]
    float* act_sf_out = fc_sf_out + OUT_DIM;                 // [1]

    char* ws = (char*)d_ws;
    float* bb   = (float*)ws;                                // 4096 floats
    float* gmax = (float*)(ws + 16384);                      // 1 float
    unsigned short* xq = (unsigned short*)(ws + 32768);      // x bf16 (64 MiB)
    unsigned short* wq = xq + (size_t)B_DIM * IN_DIM;        // w_int bf16 (32 MiB)
    unsigned short* cq = wq + (size_t)OUT_DIM * IN_DIM;      // C bf16 (64 MiB)

    size_t need = 32768 + ((size_t)B_DIM * IN_DIM + (size_t)OUT_DIM * IN_DIM
                           + (size_t)B_DIM * OUT_DIM) * 2;

    prep<<<OUT_DIM + (B_DIM * IN_DIM) / 2048, 256, 0, stream>>>(
        W, b, act_sf, x, wq, xq, fc_sf_out, bb, gmax);

    int gemm_grid = (B_DIM / 256) * (OUT_DIM / 256);         // 512 wgs, 512 thr
    int rq_grid = (B_DIM * OUT_DIM) / 4096;
    if (ws_size >= need) {
        gemm_bt<true><<<gemm_grid, 512, 0, stream>>>(
            xq, wq, fc_sf_out, bb, (void*)cq, gmax);
        requant<true><<<rq_grid, 256, 0, stream>>>(
            (const void*)cq, out, gmax, act_sf_out);
    } else {
        gemm_bt<false><<<gemm_grid, 512, 0, stream>>>(
            xq, wq, fc_sf_out, bb, (void*)out, gmax);
        requant<false><<<rq_grid, 256, 0, stream>>>(
            (const void*)out, out, gmax, act_sf_out);
    }
}

// Round 5
// 523.550 us; speedup vs baseline: 1.0546x; 1.0546x over previous
//
#include <hip/hip_runtime.h>
#include <hip/hip_bf16.h>
#include <stdint.h>

#define B_DIM 8192
#define IN_DIM 4096
#define OUT_DIM 4096
#define NT (IN_DIM / 64)   // 64 K-tiles of BK=64

typedef __attribute__((ext_vector_type(8))) short s16x8;
typedef __attribute__((ext_vector_type(4))) float f32x4;

__device__ __forceinline__ unsigned short f2bf_rn(float f) {
    unsigned int u = __float_as_uint(f);
    u = (u + 0x7FFFu + ((u >> 16) & 1u)) >> 16;
    return (unsigned short)u;
}

__device__ __forceinline__ void async16(unsigned short* l, const unsigned short* g) {
    __builtin_amdgcn_global_load_lds(
        (const __attribute__((address_space(1))) void*)g,
        (__attribute__((address_space(3))) void*)l, 16, 0, 0);
}

// ---- Kernel 1: fused weight-quant (blocks 0..4095) + x->bf16 (rest) --------
// R5: divides -> reciprocal-multiplies (16 fp32 divs/thread were ~7 VALU ops
// each); x-cast stores one 16-B s16x8 instead of 2x 8-B ushort4.
__global__ __launch_bounds__(256) void prep(
    const float* __restrict__ W, const float* __restrict__ b,
    const float* __restrict__ act_sf, const float* __restrict__ x,
    unsigned short* __restrict__ wq, unsigned short* __restrict__ xq,
    float* __restrict__ fc_sf_out, float* __restrict__ bb,
    float* __restrict__ gmax)
{
    __shared__ float red[4];
    int t = threadIdx.x;
    if (blockIdx.x < OUT_DIM) {
        int o = blockIdx.x;
        const float4* Wr = (const float4*)(W + (size_t)o * IN_DIM);
        float4 v[4];
        float amax = 0.f;
#pragma unroll
        for (int j = 0; j < 4; ++j) {
            v[j] = Wr[t + j * 256];
            amax = fmaxf(amax, fmaxf(fmaxf(fabsf(v[j].x), fabsf(v[j].y)),
                                     fmaxf(fabsf(v[j].z), fabsf(v[j].w))));
        }
#pragma unroll
        for (int off = 32; off > 0; off >>= 1)
            amax = fmaxf(amax, __shfl_down(amax, off, 64));
        if ((t & 63) == 0) red[t >> 6] = amax;
        __syncthreads();
        float wmax = fmaxf(fmaxf(red[0], red[1]), fmaxf(red[2], red[3]));
        float sf = fmaxf(wmax, 1e-8f) / 127.0f;   // fc_sf
        float rsf = 1.0f / sf;

        unsigned short* wr = wq + (size_t)o * IN_DIM;
#pragma unroll
        for (int j = 0; j < 4; ++j) {
            ushort4 q;
            q.x = f2bf_rn(fminf(fmaxf(rintf(v[j].x * rsf), -128.f), 127.f));
            q.y = f2bf_rn(fminf(fmaxf(rintf(v[j].y * rsf), -128.f), 127.f));
            q.z = f2bf_rn(fminf(fmaxf(rintf(v[j].z * rsf), -128.f), 127.f));
            q.w = f2bf_rn(fminf(fmaxf(rintf(v[j].w * rsf), -128.f), 127.f));
            ((ushort4*)wr)[t + j * 256] = q;
        }
        if (t == 0) {
            fc_sf_out[o] = sf;
            float bsf = sf * act_sf[0];          // bias_sf
            float bi = rintf(b[o] / bsf);        // b_int (one div, exact)
            bb[o] = bi * bsf;                    // folded bias
            if (o == 0) gmax[0] = 0.f;           // ws is poisoned each launch
        }
    } else {
        size_t i = ((size_t)(blockIdx.x - OUT_DIM) * 256 + t) * 8;
        float4 v0 = *(const float4*)(x + i);
        float4 v1 = *(const float4*)(x + i + 4);
        s16x8 q;
        q[0] = (short)f2bf_rn(v0.x); q[1] = (short)f2bf_rn(v0.y);
        q[2] = (short)f2bf_rn(v0.z); q[3] = (short)f2bf_rn(v0.w);
        q[4] = (short)f2bf_rn(v1.x); q[5] = (short)f2bf_rn(v1.y);
        q[6] = (short)f2bf_rn(v1.z); q[7] = (short)f2bf_rn(v1.w);
        *(s16x8*)(xq + i) = q;
    }
}

// ---- Kernel 2: 256x256-tile skewed-pipeline GEMM C = A * B^T ---------------
// EXACT R3 kernel (verified 231 us, 0.5M bank conflicts) - control for this
// round. 16x16x32 MFMA; BK=64, 8 waves (2Mx4N), 128 KiB LDS double-buffer.
// Phase order: [ds_read(for p+1); lgkmcnt(N_this); sched_barrier(0);
//   vmcnt(10); s_barrier; stage(1 half-tile); setprio(1); 16 MFMA; setprio(0)]
// vmcnt(10) drains S(p-6) in EVERY wave before the barrier that precedes the
// region's reads (per-wave vmcnt visibility discipline, R3 fix).
template <bool CB16>
__global__ __launch_bounds__(512) void gemm_bt(
    const unsigned short* __restrict__ A, const unsigned short* __restrict__ Bw,
    const float* __restrict__ fc_sf, const float* __restrict__ bb,
    void* __restrict__ Cout, float* __restrict__ gmax)
{
    __shared__ __align__(16) unsigned char smem[131072];
    unsigned short* lds = (unsigned short*)smem;   // [buf0: A 32K | buf1: A 32K | buf0: B 32K | buf1: B 32K]
    float* stage = (float*)smem;                   // epilogue 64x260 fp32
    float* redm  = (float*)(smem + 131040);        // 8 floats (used only after full drain)

    int t = threadIdx.x;
    // XCD-aware swizzle: 512 wgs, 512 % 8 == 0 -> bijective remap.
    int bid = ((blockIdx.x & 7) << 6) | (blockIdx.x >> 3);
    int bm = bid >> 4, bn = bid & 15;              // 32 x 16 tiles
    int m0 = bm << 8, n0 = bn << 8;

    int w = t >> 6, lane = t & 63;
    int wm = w & 1, wn = w >> 1;                   // 2M x 4N wave grid
    int quad = lane >> 4, l16 = lane & 15;
    int swz = l16 & 7;

    int co0 = (quad ^ swz) << 3;                   // k-half 0 chunk slot
    int co1 = ((quad + 4) ^ swz) << 3;             // k-half 1 chunk slot
    int aOff = ((wm << 4) + l16) << 6;             // A row offset (u16)
    int bOff = 32768 + (((wn << 4) + l16) << 6);   // B base (64KB) + row offset

    // Staging: half-tile = 128 rows x 64 cols bf16 = 16 KB; thread t owns
    // slot t (rows 0..63) and t+512 (rows 64..127). Source pre-swizzled.
    int r0 = t >> 3;
    int cs = ((t & 7) ^ (r0 & 7)) << 3;
    const unsigned short* gA = A + (size_t)(m0 + r0) * IN_DIM + cs;
    const unsigned short* gB = Bw + (size_t)(n0 + r0) * IN_DIM + cs;
    unsigned short* ldsA = lds + t * 8;
    unsigned short* ldsB = lds + 32768 + t * 8;

#define STA(u, hf) { int uu_ = (u) < NT ? (u) : ((u) - 2 < NT ? (u) - 2 : (u) - 4); \
    const unsigned short* s_ = gA + (size_t)((hf) * 128) * IN_DIM + uu_ * 64;       \
    unsigned short* d_ = ldsA + ((uu_ & 1) << 14) + ((hf) << 13);                   \
    async16(d_, s_); async16(d_ + 4096, s_ + (size_t)64 * IN_DIM); }
#define STB(u, hf) { int uu_ = (u) < NT ? (u) : ((u) - 2 < NT ? (u) - 2 : (u) - 4); \
    const unsigned short* s_ = gB + (size_t)((hf) * 128) * IN_DIM + uu_ * 64;       \
    unsigned short* d_ = ldsB + ((uu_ & 1) << 14) + ((hf) << 13);                   \
    async16(d_, s_); async16(d_ + 4096, s_ + (size_t)64 * IN_DIM); }

#define RD_A(dst, base) _Pragma("unroll") \
    for (int mi_ = 0; mi_ < 4; ++mi_) { \
        dst[mi_][0] = *(const s16x8*)((base) + mi_ * 2048 + co0); \
        dst[mi_][1] = *(const s16x8*)((base) + mi_ * 2048 + co1); }
#define RD_B(dst, base) _Pragma("unroll") \
    for (int nj_ = 0; nj_ < 2; ++nj_) { \
        dst[nj_][0] = *(const s16x8*)((base) + nj_ * 4096 + co0); \
        dst[nj_][1] = *(const s16x8*)((base) + nj_ * 4096 + co1); }

#define QUAD(MB, NB, AF, BF) _Pragma("unroll") \
    for (int mi_ = 0; mi_ < 4; ++mi_) { _Pragma("unroll") \
        for (int nj_ = 0; nj_ < 2; ++nj_) { \
            acc[(MB)+mi_][(NB)+nj_] = __builtin_amdgcn_mfma_f32_16x16x32_bf16( \
                AF[mi_][0], BF[nj_][0], acc[(MB)+mi_][(NB)+nj_], 0, 0, 0); \
            acc[(MB)+mi_][(NB)+nj_] = __builtin_amdgcn_mfma_f32_16x16x32_bf16( \
                AF[mi_][1], BF[nj_][1], acc[(MB)+mi_][(NB)+nj_], 0, 0, 0); } }

#define PHASE(RD, NCNT, ST, MM) \
    RD; \
    asm volatile("s_waitcnt lgkmcnt(" #NCNT ")" ::: "memory"); \
    __builtin_amdgcn_sched_barrier(0); \
    asm volatile("s_waitcnt vmcnt(10)" ::: "memory"); \
    __builtin_amdgcn_s_barrier(); \
    ST; \
    __builtin_amdgcn_s_setprio(1); \
    MM; \
    __builtin_amdgcn_s_setprio(0);

    f32x4 acc[8][4];
#pragma unroll
    for (int mi = 0; mi < 8; ++mi)
#pragma unroll
        for (int nj = 0; nj < 4; ++nj)
            acc[mi][nj] = (f32x4){0.f, 0.f, 0.f, 0.f};

    s16x8 a0[4][2], a1[4][2], b0[2][2], b1[2][2];

    // ---- prologue: bulk-stage 7 half-tiles in read order -------------------
    // S1=A(0,0) S2=B(0,0) S3=B(0,1) S4=A(0,1) S5=A(1,0) S6=B(1,0) S7=B(1,1)
    STA(0, 0); STB(0, 0); STB(0, 1); STA(0, 1); STA(1, 0); STB(1, 0); STB(1, 1);
    asm volatile("s_waitcnt vmcnt(12)" ::: "memory");   // drain S1 (all waves) ...
    __builtin_amdgcn_s_barrier();                       // ... before anyone reads it
    // p0: read A0(0)=S1; drain S2 for p1's read; stage S8=A(1,1)
    RD_A(a0, lds + aOff);
    asm volatile("s_waitcnt lgkmcnt(8)" ::: "memory");
    __builtin_amdgcn_sched_barrier(0);
    asm volatile("s_waitcnt vmcnt(10)" ::: "memory");
    __builtin_amdgcn_s_barrier();
    STA(1, 1);
    // p1: read B0(0)=S2; drain S3; stage S9=A(2,0)
    RD_B(b0, lds + bOff);
    asm volatile("s_waitcnt lgkmcnt(4)" ::: "memory");
    __builtin_amdgcn_sched_barrier(0);
    asm volatile("s_waitcnt vmcnt(10)" ::: "memory");
    __builtin_amdgcn_s_barrier();
    STA(2, 0);

    // ---- main loop: 2 K-tiles per iteration, 8 phases ----------------------
    for (int T = 0; T < NT; T += 2) {
        const unsigned short* laT  = lds + ((T & 1) << 14) + aOff;
        const unsigned short* lbT  = lds + ((T & 1) << 14) + bOff;
        const unsigned short* laT1 = lds + (((T + 1) & 1) << 14) + aOff;
        const unsigned short* lbT1 = lds + (((T + 1) & 1) << 14) + bOff;

        PHASE( RD_B(b1, lbT + 8192),  4, STB(T + 2, 0), QUAD(0, 0, a0, b0) ); // Q00(T)
        PHASE( RD_A(a1, laT + 8192),  8, STB(T + 2, 1), QUAD(0, 2, a0, b1) ); // Q01(T)
        PHASE( RD_A(a0, laT1),        8, STA(T + 2, 1), QUAD(4, 0, a1, b0) ); // Q10(T)
        PHASE( RD_B(b0, lbT1),        4, STA(T + 3, 0), QUAD(4, 2, a1, b1) ); // Q11(T)
        PHASE( RD_B(b1, lbT1 + 8192), 4, STB(T + 3, 0), QUAD(0, 0, a0, b0) ); // Q00(T+1)
        PHASE( RD_A(a1, laT1 + 8192), 8, STB(T + 3, 1), QUAD(0, 2, a0, b1) ); // Q01(T+1)
        PHASE( RD_A(a0, laT),         8, STA(T + 3, 1), QUAD(4, 0, a1, b0) ); // Q10(T+1)
        PHASE( RD_B(b0, lbT),         4, STA(T + 4, 0), QUAD(4, 2, a1, b1) ); // Q11(T+1)
    }

    // drain all pending global_load_lds / ds ops before LDS reuse (redm in B-buf1)
    asm volatile("s_waitcnt vmcnt(0) lgkmcnt(0)" ::: "memory");
    __syncthreads();

    // ---- epilogue: scale+bias+ReLU, track max ------------------------------
    float sc[4], bv[4];
#pragma unroll
    for (int nj = 0; nj < 4; ++nj) {
        int col = n0 + (((nj << 2) + wn) << 4) + l16;
        sc[nj] = fc_sf[col];
        bv[nj] = bb[col];
    }
    float tmax = 0.f;
#pragma unroll
    for (int mi = 0; mi < 8; ++mi)
#pragma unroll
        for (int nj = 0; nj < 4; ++nj)
#pragma unroll
            for (int r = 0; r < 4; ++r) {
                float vv = fmaxf(acc[mi][nj][r] * sc[nj] + bv[nj], 0.f);
                acc[mi][nj][r] = vv;
                tmax = fmaxf(tmax, vv);
            }
#pragma unroll
    for (int off = 32; off > 0; off >>= 1)
        tmax = fmaxf(tmax, __shfl_down(tmax, off, 64));
    if (lane == 0) redm[w] = tmax;

    // ---- 4-phase LDS transpose -> contiguous (bf16) C stores ---------------
#pragma unroll
    for (int ph = 0; ph < 4; ++ph) {
        __syncthreads();
#pragma unroll
        for (int ml = 0; ml < 2; ++ml) {
            int lrow = (((ml << 1) + wm) << 4) + (quad << 2);
#pragma unroll
            for (int nj = 0; nj < 4; ++nj) {
                int col = (((nj << 2) + wn) << 4) + l16;
#pragma unroll
                for (int r = 0; r < 4; ++r)
                    stage[(lrow + r) * 260 + col] = acc[ph * 2 + ml][nj][r];
            }
        }
        __syncthreads();
        int row = t >> 3, ch = t & 7;
        const float* src = stage + row * 260 + ch * 32;
        size_t gbase = (size_t)(m0 + ph * 64 + row) * OUT_DIM + n0 + ch * 32;
        if (CB16) {
            unsigned short* dst = (unsigned short*)Cout + gbase;
#pragma unroll
            for (int j = 0; j < 4; ++j) {
                float4 v0 = *(const float4*)(src + j * 8);
                float4 v1 = *(const float4*)(src + j * 8 + 4);
                s16x8 q;
                q[0] = (short)f2bf_rn(v0.x); q[1] = (short)f2bf_rn(v0.y);
                q[2] = (short)f2bf_rn(v0.z); q[3] = (short)f2bf_rn(v0.w);
                q[4] = (short)f2bf_rn(v1.x); q[5] = (short)f2bf_rn(v1.y);
                q[6] = (short)f2bf_rn(v1.z); q[7] = (short)f2bf_rn(v1.w);
                *(s16x8*)(dst + j * 8) = q;
            }
        } else {
            float* dst = (float*)Cout + gbase;
#pragma unroll
            for (int j = 0; j < 8; ++j)
                *(float4*)(dst + j * 4) = *(const float4*)(src + j * 4);
        }
    }
    if (t == 0) {
        float bmax = redm[0];
#pragma unroll
        for (int i = 1; i < 8; ++i) bmax = fmaxf(bmax, redm[i]);
        atomicMax((int*)gmax, __float_as_int(bmax));   // values >= 0
    }
#undef STA
#undef STB
#undef RD_A
#undef RD_B
#undef QUAD
#undef PHASE
}

// ---- Kernel 3: per-tensor requant, 16 elems/thread -------------------------
// R5: 16-B s16x8 loads (was 8-B ushort4); div -> reciprocal-multiply.
// x_min = 0 exactly (post-ReLU) -> zp = 0.
template <bool CB16>
__global__ __launch_bounds__(256) void requant(const void* __restrict__ Cin,
    float* __restrict__ out, const float* __restrict__ gmax,
    float* __restrict__ sf_out)
{
    float sf = fmaxf(gmax[0], 1e-8f) / 255.0f;
    float rs = 1.0f / sf;
    size_t i = ((size_t)blockIdx.x * 256 + threadIdx.x) * 16;
    if (CB16) {
        const unsigned short* cq = (const unsigned short*)Cin + i;
#pragma unroll
        for (int j = 0; j < 2; ++j) {
            s16x8 q = *(const s16x8*)(cq + j * 8);
            float f[8];
#pragma unroll
            for (int k = 0; k < 8; ++k) {
                float v = __uint_as_float((unsigned)(unsigned short)q[k] << 16);
                f[k] = fminf(rintf(v * rs), 255.f) * sf;
            }
            float4 o0 = {f[0], f[1], f[2], f[3]};
            float4 o1 = {f[4], f[5], f[6], f[7]};
            *(float4*)(out + i + j * 8) = o0;
            *(float4*)(out + i + j * 8 + 4) = o1;
        }
    } else {
        float* C = out;   // in place
#pragma unroll
        for (int j = 0; j < 4; ++j) {
            float4 v = *(const float4*)(C + i + j * 4);
            v.x = fminf(rintf(v.x * rs), 255.f) * sf;
            v.y = fminf(rintf(v.y * rs), 255.f) * sf;
            v.z = fminf(rintf(v.z * rs), 255.f) * sf;
            v.w = fminf(rintf(v.w * rs), 255.f) * sf;
            *(float4*)(C + i + j * 4) = v;
        }
    }
    if (i == 0) sf_out[0] = sf;
}

extern "C" void kernel_launch(void* const* d_in, const int* in_sizes, int n_in,
                              void* d_out, int out_size, void* d_ws, size_t ws_size,
                              hipStream_t stream)
{
    const float* x      = (const float*)d_in[0];
    const float* act_sf = (const float*)d_in[1];
    const float* W      = (const float*)d_in[2];
    const float* b      = (const float*)d_in[3];

    float* out        = (float*)d_out;                       // [8192*4096] x_out
    float* fc_sf_out  = out + (size_t)B_DIM * OUT_DIM;       // [4096]
    float* act_sf_out = fc_sf_out + OUT_DIM;                 // [1]

    char* ws = (char*)d_ws;
    float* bb   = (float*)ws;                                // 4096 floats
    float* gmax = (float*)(ws + 16384);                      // 1 float
    unsigned short* xq = (unsigned short*)(ws + 32768);      // x bf16 (64 MiB)
    unsigned short* wq = xq + (size_t)B_DIM * IN_DIM;        // w_int bf16 (32 MiB)
    unsigned short* cq = wq + (size_t)OUT_DIM * IN_DIM;      // C bf16 (64 MiB)

    size_t need = 32768 + ((size_t)B_DIM * IN_DIM + (size_t)OUT_DIM * IN_DIM
                           + (size_t)B_DIM * OUT_DIM) * 2;

    prep<<<OUT_DIM + (B_DIM * IN_DIM) / 2048, 256, 0, stream>>>(
        W, b, act_sf, x, wq, xq, fc_sf_out, bb, gmax);

    int gemm_grid = (B_DIM / 256) * (OUT_DIM / 256);         // 512 wgs, 512 thr
    int rq_grid = (B_DIM * OUT_DIM) / 4096;
    if (ws_size >= need) {
        gemm_bt<true><<<gemm_grid, 512, 0, stream>>>(
            xq, wq, fc_sf_out, bb, (void*)cq, gmax);
        requant<true><<<rq_grid, 256, 0, stream>>>(
            (const void*)cq, out, gmax, act_sf_out);
    } else {
        gemm_bt<false><<<gemm_grid, 512, 0, stream>>>(
            xq, wq, fc_sf_out, bb, (void*)out, gmax);
        requant<false><<<rq_grid, 256, 0, stream>>>(
            (const void*)out, out, gmax, act_sf_out);
    }
}